// Round 15
// baseline (107.635 us; speedup 1.0000x reference)
//
#include <hip/hip_runtime.h>
#include <hip/hip_bf16.h>
#include <math.h>

#define NROWS 16384
#define DIN   784
#define DZ    100
#define NS    10
#define NCT   16           // 16 col-tiles x 16 = 256 cols (200 real + 56 zero pad)
#define KTILES 25          // 25 * 32 = 800 >= 784, tail frags zeroed
#define BND_THR 45.0f
#define KTPAD 520          // kt-stride in ushorts (1040B)
#define NBLK  256          // fused grid: 1 block/CU, co-resident

typedef unsigned short ushort_t;
typedef short bf16x8 __attribute__((ext_vector_type(8)));
typedef float f32x4  __attribute__((ext_vector_type(4)));

// ws: [0..199] colsums (atomic)  [200] pv sum  [202] ctr1  [203] ctr2
//     [208..8047] y2 (fallback path only)
// byte 64KB..: Wb bf16 frag-swizzled W (400 KB)
#define WS_Y2 208
#define WB_OFF_BYTES (64u * 1024u)

// fused-kernel LDS layout (byte offsets)
#define XLS_OFF   0         // 4*25*520*2      = 104000
#define YF_OFF    104000    // 25*512*2        =  25600
#define MCOV_OFF  129600    // 200*4           =    800
#define ZL_OFF    130400    // 1000*4          =   4000
#define RED_OFF   134400    // 16*64*4*4       =  16384
#define FLAGS_OFF 150784    // ints
#define SMEM_SZ   150800

__device__ __forceinline__ float softplus_fast(float v) {
    float t = v * 1.44269504088896f;
    return (fmaxf(t, 0.f)
            + __builtin_amdgcn_logf(1.f + __builtin_amdgcn_exp2f(-fabsf(t))))
           * 0.69314718055995f;
}
__device__ __forceinline__ unsigned pack2(float lo, float hi) {
    float2 f2; f2.x = lo; f2.y = hi;
    __hip_bfloat162 h2 = __float22bfloat162_rn(f2);
    return *reinterpret_cast<unsigned*>(&h2);
}

// ---- W -> bf16 B-frags + ws zero ----
__global__ __launch_bounds__(256) void wb_kernel(
    const float* __restrict__ W0, const float* __restrict__ W1,
    ushort_t* __restrict__ Wb, float* __restrict__ ws)
{
    if (blockIdx.x == 0) ws[threadIdx.x] = 0.f;    // sums + both counters
    int t = blockIdx.x * 256 + threadIdx.x;
    if (t >= KTILES * NCT * 64) return;
    int kt = t >> 10;
    int r  = t & 1023;
    int ct = r >> 6, l = r & 63;
    int col = ct * 16 + (l & 15);
    int k0  = kt * 32 + (l >> 4) * 8;
    uint4 o = make_uint4(0u, 0u, 0u, 0u);
    if (col < 200 && k0 < DIN) {
        const float* src = (col < 100 ? W0 + (size_t)col * DIN
                                      : W1 + (size_t)(col - 100) * DIN) + k0;
        float4 a = *(const float4*)src;
        float4 b = *(const float4*)(src + 4);
        o.x = pack2(a.x, a.y); o.y = pack2(a.z, a.w);
        o.z = pack2(b.x, b.y); o.w = pack2(b.z, b.w);
    }
    *(uint4*)(Wb + (size_t)t * 8) = o;
}

// ================= FUSED: colmean -> grid-barrier -> y2 -> pv -> final ==========
__global__ __launch_bounds__(1024) void fused_kernel(
    const float* __restrict__ x, const ushort_t* __restrict__ Wb,
    const float* __restrict__ b0, const float* __restrict__ b1,
    const float* __restrict__ W2, const float* __restrict__ b2,
    const float* __restrict__ eps, float* __restrict__ ws,
    float* __restrict__ out)
{
    __shared__ __align__(16) unsigned char smem[SMEM_SZ];
    ushort_t* xls  = (ushort_t*)(smem + XLS_OFF);
    ushort_t* yfp  = (ushort_t*)(smem + YF_OFF);
    float*    mcov = (float*)(smem + MCOV_OFF);
    float*    zl   = (float*)(smem + ZL_OFF);
    float*    redp = (float*)(smem + RED_OFF);
    int*      flags= (int*)(smem + FLAGS_OFF);

    const int tid = threadIdx.x;
    const int lane = tid & 63, w = tid >> 6;
    const int row0 = blockIdx.x * 64;
    if (tid == 0) flags[0] = 0;

    // ---- Phase A1: stage x -> bf16 A-frags in LDS (coalesced reads) ----
    for (int slot = tid; slot < 6400; slot += 1024) {  // slot = r*100 + kt*4 + kc
        int r  = slot / 100;
        int sl = slot - r * 100;
        int kt = sl >> 2, kc = sl & 3;
        int k0 = kt * 32 + kc * 8;
        uint4 o = make_uint4(0u, 0u, 0u, 0u);
        if (k0 + 8 <= DIN) {
            const float* src = x + (size_t)(row0 + r) * DIN + k0;
            float4 a = *(const float4*)src, b = *(const float4*)(src + 4);
            o.x = pack2(a.x, a.y); o.y = pack2(a.z, a.w);
            o.z = pack2(b.x, b.y); o.w = pack2(b.z, b.w);
        }
        int l = (kc << 4) | (r & 15);
        *(uint4*)&xls[((size_t)(r >> 4) * KTILES + kt) * KTPAD + l * 8] = o;
    }
    __syncthreads();

    // ---- Phase A2: colmean K-loop (R14-proven shape) ----
    {
        const int rt = w >> 2, ct0 = (w & 3) * 4;
        const ushort_t* ap  = xls + (size_t)rt * KTILES * KTPAD + lane * 8;
        const ushort_t* wbp = Wb + (size_t)ct0 * 512 + lane * 8;

        f32x4 acc[4];
#pragma unroll
        for (int jj = 0; jj < 4; ++jj) acc[jj] = (f32x4){0.f, 0.f, 0.f, 0.f};

        bf16x8 Aa, Ab;
        uint4  Ba[4], Bb[4];
        auto ld = [&](int kt, bf16x8& A, uint4 (&B)[4]) {
            A = *(const bf16x8*)(ap + (size_t)kt * KTPAD);
#pragma unroll
            for (int jj = 0; jj < 4; ++jj)
                B[jj] = *(const uint4*)(wbp + (size_t)kt * 8192 + jj * 512);
        };
        auto cp = [&](const bf16x8& A, const uint4 (&B)[4]) {
#pragma unroll
            for (int jj = 0; jj < 4; ++jj)
                acc[jj] = __builtin_amdgcn_mfma_f32_16x16x32_bf16(
                    A, *(const bf16x8*)&B[jj], acc[jj], 0, 0, 0);
        };
        ld(0, Aa, Ba);
        for (int i = 0; i < 12; ++i) {
            ld(2 * i + 1, Ab, Bb);
            cp(Aa, Ba);
            ld(2 * i + 2, Aa, Ba);
            cp(Ab, Bb);
        }
        cp(Aa, Ba);                        // kt = 24

        float vj[4];
#pragma unroll
        for (int jj = 0; jj < 4; ++jj) {
            int j = (ct0 + jj) * 16 + (lane & 15);
            float bias = (j < 100) ? b0[j] : ((j < 200) ? b1[j - 100] : 0.f);
            float v = 0.f;
#pragma unroll
            for (int r = 0; r < 4; ++r) v += softplus_fast(acc[jj][r] + bias);
            v += __shfl_xor(v, 16);
            v += __shfl_xor(v, 32);
            vj[jj] = v;
        }
        if (rt > 0 && (lane >> 4) == 0) {
#pragma unroll
            for (int jj = 0; jj < 4; ++jj)
                redp[(((rt - 1) * 4 + (w & 3)) * 4 + jj) * 16 + (lane & 15)] = vj[jj];
        }
        __syncthreads();
        if (rt == 0 && (lane >> 4) == 0) {
#pragma unroll
            for (int jj = 0; jj < 4; ++jj) {
                int j = (ct0 + jj) * 16 + (lane & 15);
                float v = vj[jj]
                        + redp[((0 + (w & 3)) * 4 + jj) * 16 + (lane & 15)]
                        + redp[((4 + (w & 3)) * 4 + jj) * 16 + (lane & 15)]
                        + redp[((8 + (w & 3)) * 4 + jj) * 16 + (lane & 15)];
                if (j < 200) atomicAdd(&ws[j], v);
            }
        }
        __syncthreads();                   // drains the atomics of all waves
    }

    // ---- Phase B: device-wide barrier (co-resident: cooperative launch) ----
    if (tid == 0) {
        __threadfence();
        atomicAdd((unsigned*)&ws[202], 1u);
        while (__hip_atomic_load((unsigned*)&ws[202], __ATOMIC_RELAXED,
                                 __HIP_MEMORY_SCOPE_AGENT) < (unsigned)NBLK) {
            __builtin_amdgcn_s_sleep(2);
        }
    }
    __syncthreads();

    // ---- Phase C: mean/cov, z, y2 -> frags (redundant per block, all in LDS) ----
    if (tid < 200)
        mcov[tid] = __hip_atomic_load(&ws[tid], __ATOMIC_RELAXED,
                                      __HIP_MEMORY_SCOPE_AGENT) * (1.f / (float)NROWS);
    for (int i2 = tid; i2 < 1600; i2 += 1024)      // zero yf (pad lanes/tail)
        ((uint4*)yfp)[i2] = make_uint4(0u, 0u, 0u, 0u);
    __syncthreads();
    if (tid < 1000) {
        int s = tid / 100, d = tid - s * 100;
        zl[tid] = mcov[d] + mcov[100 + d] * eps[s * DZ + d];
    }
    __syncthreads();
    for (int i = tid; i < DIN; i += 1024) {        // 784 active threads
        const float* wr = W2 + (size_t)i * DZ;
        float p[NS];
#pragma unroll
        for (int s = 0; s < NS; ++s) p[s] = 0.f;
        for (int d4 = 0; d4 < DZ; d4 += 4) {
            float4 wv = *(const float4*)(wr + d4);
#pragma unroll
            for (int s = 0; s < NS; ++s) {
                const float* zs = zl + s * DZ + d4;
                p[s] += wv.x * zs[0] + wv.y * zs[1] + wv.z * zs[2] + wv.w * zs[3];
            }
        }
        float bb = b2[i];
        int kt = i >> 5, k = i & 31, ks2 = k >> 3, j = k & 7;
#pragma unroll
        for (int s = 0; s < NS; ++s) {
            float v = (p[s] + bb) * 1.4426950408889634f;
            __hip_bfloat16 h = __float2bfloat16(v);
            yfp[((size_t)(kt * 64 + ks2 * 16 + s)) * 8 + j] = *(ushort_t*)&h;
        }
    }
    __syncthreads();

    // ---- Phase D: pv on resident x-frags (16 waves: 4 rowtiles x 4 K-split) ----
    {
        const int rt = w >> 2, kseg = w & 3;
        const ushort_t* ap = xls + (size_t)rt * KTILES * KTPAD + lane * 8;
        f32x4 acc0 = (f32x4){0.f, 0.f, 0.f, 0.f};
        f32x4 acc1 = (f32x4){0.f, 0.f, 0.f, 0.f};
        for (int kt = kseg; kt < KTILES; kt += 4) {
            uint4 X = *(const uint4*)(ap + (size_t)kt * KTPAD);
            bf16x8 nf; unsigned* p = (unsigned*)&nf;
            const unsigned* xw = (const unsigned*)&X;
#pragma unroll
            for (int i2 = 0; i2 < 4; ++i2) {
                float lo = __uint_as_float(xw[i2] << 16);
                float hi = __uint_as_float(xw[i2] & 0xFFFF0000u);
                p[i2] = pack2(1.f - 2.f * lo, 1.f - 2.f * hi);
            }
            bf16x8 na; unsigned* q = (unsigned*)&na;
            q[0] = p[0] & 0x7FFF7FFFu; q[1] = p[1] & 0x7FFF7FFFu;
            q[2] = p[2] & 0x7FFF7FFFu; q[3] = p[3] & 0x7FFF7FFFu;
            bf16x8 fy = *(const bf16x8*)(yfp + (size_t)kt * 512 + lane * 8);
            bf16x8 fa; unsigned* fq = (unsigned*)&fa;
            const unsigned* fp = (const unsigned*)&fy;
            fq[0] = fp[0] & 0x7FFF7FFFu; fq[1] = fp[1] & 0x7FFF7FFFu;
            fq[2] = fp[2] & 0x7FFF7FFFu; fq[3] = fp[3] & 0x7FFF7FFFu;
            acc0 = __builtin_amdgcn_mfma_f32_16x16x32_bf16(nf, fy, acc0, 0, 0, 0);
            acc1 = __builtin_amdgcn_mfma_f32_16x16x32_bf16(na, fa, acc1, 0, 0, 0);
        }
#pragma unroll
        for (int r = 0; r < 4; ++r)
            redp[((size_t)w * 64 + lane) * 4 + r] = 0.5f * (acc0[r] + acc1[r]);
        __syncthreads();

        if (kseg == 0) {
            const int s = lane & 15;
            const float L001 = -6.90775527898f;
            float bnd[4];
#pragma unroll
            for (int r = 0; r < 4; ++r)
                bnd[r] = redp[(((rt * 4 + 0) * 64) + lane) * 4 + r]
                       + redp[(((rt * 4 + 1) * 64) + lane) * 4 + r]
                       + redp[(((rt * 4 + 2) * 64) + lane) * 4 + r]
                       + redp[(((rt * 4 + 3) * 64) + lane) * 4 + r];
            float wsum;
            bool lslow = (s < NS) &&
                (fminf(fminf(bnd[0], bnd[1]), fminf(bnd[2], bnd[3])) < BND_THR);
            unsigned long long m = __ballot(lslow);
            if (m == 0ull) {
                wsum = 160.f * L001;
            } else {
                int nslow = 0;
                float slowsum = 0.f;
#pragma unroll
                for (int r = 0; r < 4; ++r) {
                    unsigned long long mr = __ballot((s < NS) && (bnd[r] < BND_THR));
                    nslow += (int)__popcll(mr);
                    while (mr) {
                        int src = (int)__ffsll(mr) - 1; mr &= (mr - 1);
                        int ss = src & 15;
                        int rrow = row0 + rt * 16 + (src >> 4) * 4 + r;
                        const float* xq = x + (size_t)rrow * DIN;
                        const float* zs = zl + ss * DZ;
                        float a = 0.f;
                        for (int i = lane; i < DIN; i += 64) {
                            const float* wr = W2 + (size_t)i * DZ;
                            float yi = 0.f;
                            for (int d4 = 0; d4 < DZ; d4 += 4) {
                                float4 wv = *(const float4*)(wr + d4);
                                yi += wv.x * zs[d4] + wv.y * zs[d4 + 1]
                                    + wv.z * zs[d4 + 2] + wv.w * zs[d4 + 3];
                            }
                            float y2i = (yi + b2[i]) * 1.4426950408889634f;
                            a -= __builtin_amdgcn_logf(
                                1.f + __builtin_amdgcn_exp2f((1.f - 2.f * xq[i]) * y2i));
                        }
#pragma unroll
                        for (int off = 32; off > 0; off >>= 1) a += __shfl_xor(a, off);
                        slowsum += __logf(__builtin_amdgcn_exp2f(a) + 0.001f);
                    }
                }
                wsum = (float)(160 - nslow) * L001 + slowsum;
            }
            if (lane == 0) atomicAdd(&ws[200], wsum);
        }
        __syncthreads();                   // drains pv atomics
    }

    // ---- Phase E: last block computes Dkl + output ----
    if (tid == 0) {
        unsigned old = atomicAdd((unsigned*)&ws[203], 1u);
        flags[0] = (old == (unsigned)(NBLK - 1)) ? 1 : 0;
    }
    __syncthreads();
    if (flags[0]) {
        float contrib = 0.f;
        if (tid < DZ) {
            float mm = mcov[tid], cc = mcov[100 + tid];
            contrib = 0.5f * __logf(cc);
#pragma unroll
            for (int s = 0; s < NS; ++s) {
                float e = eps[s * DZ + tid];
                float zz = mm + cc * e;
                contrib += (0.5f * cc * e * e - 0.5f * zz * zz) * (1.f / NS);
            }
        }
        redp[tid] = contrib;
        __syncthreads();
        for (int off = 512; off > 0; off >>= 1) {
            if (tid < off) redp[tid] += redp[tid + off];
            __syncthreads();
        }
        if (tid == 0) {
            float S = __hip_atomic_load(&ws[200], __ATOMIC_RELAXED,
                                        __HIP_MEMORY_SCOPE_AGENT);
            out[0] = -(S * (1.f / ((float)NROWS * (float)NS)) + redp[0]);
        }
    }
}

// ================= R14 fallback pipeline (used if coop launch unavailable) ======
__global__ __launch_bounds__(1024) void colmean_g(
    const float* __restrict__ x, const ushort_t* __restrict__ Wb,
    const float* __restrict__ b0, const float* __restrict__ b1,
    float* __restrict__ ws)
{
    __shared__ ushort_t xls[4 * KTILES * KTPAD];
    __shared__ float red2[12][4][16];
    const int tid = threadIdx.x;
    const int lane = tid & 63, w = tid >> 6;
    const int row0 = blockIdx.x * 64;

    for (int slot = tid; slot < 6400; slot += 1024) {
        int r  = slot / 100;
        int sl = slot - r * 100;
        int kt = sl >> 2, kc = sl & 3;
        int k0 = kt * 32 + kc * 8;
        uint4 o = make_uint4(0u, 0u, 0u, 0u);
        if (k0 + 8 <= DIN) {
            const float* src = x + (size_t)(row0 + r) * DIN + k0;
            float4 a = *(const float4*)src, b = *(const float4*)(src + 4);
            o.x = pack2(a.x, a.y); o.y = pack2(a.z, a.w);
            o.z = pack2(b.x, b.y); o.w = pack2(b.z, b.w);
        }
        int l = (kc << 4) | (r & 15);
        *(uint4*)&xls[((size_t)(r >> 4) * KTILES + kt) * KTPAD + l * 8] = o;
    }
    __syncthreads();

    const int rt = w >> 2, ct0 = (w & 3) * 4;
    const ushort_t* ap  = xls + (size_t)rt * KTILES * KTPAD + lane * 8;
    const ushort_t* wbp = Wb + (size_t)ct0 * 512 + lane * 8;

    f32x4 acc[4];
#pragma unroll
    for (int jj = 0; jj < 4; ++jj) acc[jj] = (f32x4){0.f, 0.f, 0.f, 0.f};
    bf16x8 Aa, Ab;
    uint4  Ba[4], Bb[4];
    auto ld = [&](int kt, bf16x8& A, uint4 (&B)[4]) {
        A = *(const bf16x8*)(ap + (size_t)kt * KTPAD);
#pragma unroll
        for (int jj = 0; jj < 4; ++jj)
            B[jj] = *(const uint4*)(wbp + (size_t)kt * 8192 + jj * 512);
    };
    auto cp = [&](const bf16x8& A, const uint4 (&B)[4]) {
#pragma unroll
        for (int jj = 0; jj < 4; ++jj)
            acc[jj] = __builtin_amdgcn_mfma_f32_16x16x32_bf16(
                A, *(const bf16x8*)&B[jj], acc[jj], 0, 0, 0);
    };
    ld(0, Aa, Ba);
    for (int i = 0; i < 12; ++i) {
        ld(2 * i + 1, Ab, Bb);
        cp(Aa, Ba);
        ld(2 * i + 2, Aa, Ba);
        cp(Ab, Bb);
    }
    cp(Aa, Ba);

    float vj[4];
#pragma unroll
    for (int jj = 0; jj < 4; ++jj) {
        int j = (ct0 + jj) * 16 + (lane & 15);
        float bias = (j < 100) ? b0[j] : ((j < 200) ? b1[j - 100] : 0.f);
        float v = 0.f;
#pragma unroll
        for (int r = 0; r < 4; ++r) v += softplus_fast(acc[jj][r] + bias);
        v += __shfl_xor(v, 16);
        v += __shfl_xor(v, 32);
        vj[jj] = v;
    }
    if (rt > 0 && (lane >> 4) == 0) {
#pragma unroll
        for (int jj = 0; jj < 4; ++jj)
            red2[(rt - 1) * 4 + (w & 3)][jj][lane & 15] = vj[jj];
    }
    __syncthreads();
    if (rt == 0 && (lane >> 4) == 0) {
#pragma unroll
        for (int jj = 0; jj < 4; ++jj) {
            int j = (ct0 + jj) * 16 + (lane & 15);
            float v = vj[jj]
                    + red2[0 + (w & 3)][jj][lane & 15]
                    + red2[4 + (w & 3)][jj][lane & 15]
                    + red2[8 + (w & 3)][jj][lane & 15];
            if (j < 200) atomicAdd(&ws[j], v);
        }
    }
}

__global__ __launch_bounds__(256) void y2z_kernel(
    const float* __restrict__ W2, const float* __restrict__ b2,
    const float* __restrict__ eps, float* __restrict__ ws)
{
    int wid  = (int)((blockIdx.x * 256 + threadIdx.x) >> 6);
    int lane = threadIdx.x & 63;
    if (wid >= NS * DIN) return;
    int s = wid / DIN, i = wid % DIN;
    const float inv = 1.f / (float)NROWS;
    const float* wr = W2 + (size_t)i * DZ;
    const float* er = eps + (size_t)s * DZ;
    float p = 0.f;
    for (int d = lane; d < DZ; d += 64) {
        float zd = inv * (ws[d] + ws[100 + d] * er[d]);
        p += zd * wr[d];
    }
#pragma unroll
    for (int off = 32; off > 0; off >>= 1) p += __shfl_xor(p, off);
    if (lane == 0) ws[WS_Y2 + wid] = (p + b2[i]) * 1.4426950408889634f;
}

__global__ __launch_bounds__(256, 4) void pv_final_kernel(
    const float* __restrict__ x, float* __restrict__ ws,
    const float* __restrict__ eps, float* __restrict__ out, int nblocks)
{
    __shared__ ushort_t yf[KTILES * 512];
    __shared__ ushort_t ya[KTILES * 512];
    __shared__ float bsum;
    __shared__ int lastflag;
    __shared__ float dred[256];
    const int tid = threadIdx.x;
    const int lane = tid & 63, w = tid >> 6;

    for (int idx = tid; idx < KTILES * 64; idx += 256) {
        int kt = idx >> 6, l = idx & 63;
        int ss = l & 15, k0 = kt * 32 + (l >> 4) * 8;
        uint4 o = make_uint4(0u, 0u, 0u, 0u), oa = o;
        if (ss < NS && k0 < DIN) {
            const float* src = ws + WS_Y2 + ss * DIN + k0;
            float4 a = *(const float4*)src, b = *(const float4*)(src + 4);
            o.x = pack2(a.x, a.y); o.y = pack2(a.z, a.w);
            o.z = pack2(b.x, b.y); o.w = pack2(b.z, b.w);
            oa.x = o.x & 0x7FFF7FFFu; oa.y = o.y & 0x7FFF7FFFu;
            oa.z = o.z & 0x7FFF7FFFu; oa.w = o.w & 0x7FFF7FFFu;
        }
        *(uint4*)(yf + (size_t)idx * 8) = o;
        *(uint4*)(ya + (size_t)idx * 8) = oa;
    }
    if (tid == 0) { bsum = 0.f; lastflag = 0; }
    __syncthreads();

    const int tile = blockIdx.x * 4 + w;
    const int row  = tile * 16 + (lane & 15);
    const int kc   = lane >> 4;
    const int s    = lane & 15;
    const float* xp = x + (size_t)row * DIN;
    const float L001 = -6.90775527898f;

    f32x4 acc0 = (f32x4){0.f, 0.f, 0.f, 0.f};
    f32x4 acc1 = (f32x4){0.f, 0.f, 0.f, 0.f};
    float4 a0A, a1A, a0B, a1B;

    auto loadA = [&](int kt, float4& a0, float4& a1) {
        int k0 = kt * 32 + kc * 8;
        if (k0 + 8 > DIN) k0 = 768;
        a0 = *(const float4*)(xp + k0);
        a1 = *(const float4*)(xp + k0 + 4);
    };
    auto comp = [&](int kt, const float4& a0, const float4& a1) {
        bf16x8 nf; unsigned* p = (unsigned*)&nf;
        p[0] = pack2(1.f - 2.f * a0.x, 1.f - 2.f * a0.y);
        p[1] = pack2(1.f - 2.f * a0.z, 1.f - 2.f * a0.w);
        p[2] = pack2(1.f - 2.f * a1.x, 1.f - 2.f * a1.y);
        p[3] = pack2(1.f - 2.f * a1.z, 1.f - 2.f * a1.w);
        bf16x8 na; unsigned* q = (unsigned*)&na;
        q[0] = p[0] & 0x7FFF7FFFu; q[1] = p[1] & 0x7FFF7FFFu;
        q[2] = p[2] & 0x7FFF7FFFu; q[3] = p[3] & 0x7FFF7FFFu;
        bf16x8 fy = *(const bf16x8*)(yf + (size_t)kt * 512 + lane * 8);
        bf16x8 fa = *(const bf16x8*)(ya + (size_t)kt * 512 + lane * 8);
        acc0 = __builtin_amdgcn_mfma_f32_16x16x32_bf16(nf, fy, acc0, 0, 0, 0);
        acc1 = __builtin_amdgcn_mfma_f32_16x16x32_bf16(na, fa, acc1, 0, 0, 0);
    };
    loadA(0, a0A, a1A);
    for (int i = 0; i < 12; ++i) {
        loadA(2 * i + 1, a0B, a1B);
        comp(2 * i, a0A, a1A);
        loadA(2 * i + 2, a0A, a1A);
        comp(2 * i + 1, a0B, a1B);
    }
    comp(24, a0A, a1A);

    float bnd[4];
#pragma unroll
    for (int r = 0; r < 4; ++r) bnd[r] = 0.5f * (acc0[r] + acc1[r]);
    float wsum;
    bool lslow = (s < NS) &&
        (fminf(fminf(bnd[0], bnd[1]), fminf(bnd[2], bnd[3])) < BND_THR);
    unsigned long long m = __ballot(lslow);
    if (m == 0ull) {
        wsum = 160.f * L001;
    } else {
        int nslow = 0;
        float slowsum = 0.f;
#pragma unroll
        for (int r = 0; r < 4; ++r) {
            unsigned long long mr = __ballot((s < NS) && (bnd[r] < BND_THR));
            nslow += (int)__popcll(mr);
            while (mr) {
                int src = (int)__ffsll(mr) - 1; mr &= (mr - 1);
                int ss = src & 15;
                int rrow = tile * 16 + (src >> 4) * 4 + r;
                const float* xq = x + (size_t)rrow * DIN;
                const float* yq = ws + WS_Y2 + ss * DIN;
                float a = 0.f;
                for (int i = lane; i < DIN; i += 64)
                    a -= __builtin_amdgcn_logf(
                        1.f + __builtin_amdgcn_exp2f((1.f - 2.f * xq[i]) * yq[i]));
#pragma unroll
                for (int off = 32; off > 0; off >>= 1) a += __shfl_xor(a, off);
                slowsum += __logf(__builtin_amdgcn_exp2f(a) + 0.001f);
            }
        }
        wsum = (float)(160 - nslow) * L001 + slowsum;
    }
    if (lane == 0) atomicAdd(&bsum, wsum);
    __syncthreads();

    if (tid == 0) {
        atomicAdd(&ws[200], bsum);
        __threadfence();
        unsigned old = atomicAdd((unsigned*)&ws[203], 1u);
        if (old == (unsigned)(nblocks - 1)) lastflag = 1;
    }
    __syncthreads();
    if (lastflag) {
        __threadfence();
        float contrib = 0.f;
        if (tid < DZ) {
            const float inv = 1.f / (float)NROWS;
            float mm = ws[tid] * inv;
            float cc = ws[100 + tid] * inv;
            contrib = 0.5f * __logf(cc);
#pragma unroll
            for (int ss2 = 0; ss2 < NS; ++ss2) {
                float e = eps[ss2 * DZ + tid];
                float zz = mm + cc * e;
                contrib += (0.5f * cc * e * e - 0.5f * zz * zz) * (1.f / NS);
            }
        }
        dred[tid] = contrib;
        __syncthreads();
        for (int off = 128; off > 0; off >>= 1) {
            if (tid < off) dred[tid] += dred[tid + off];
            __syncthreads();
        }
        if (tid == 0) {
            float S = atomicAdd(&ws[200], 0.f);
            float E = S * (1.f / ((float)NROWS * (float)NS));
            out[0] = -(E + dred[0]);
        }
    }
}

extern "C" void kernel_launch(void* const* d_in, const int* in_sizes, int n_in,
                              void* d_out, int out_size, void* d_ws, size_t ws_size,
                              hipStream_t stream)
{
    const float* x   = (const float*)d_in[0];
    const float* W0  = (const float*)d_in[1];
    const float* b0  = (const float*)d_in[2];
    const float* W1  = (const float*)d_in[3];
    const float* b1  = (const float*)d_in[4];
    const float* W2  = (const float*)d_in[5];
    const float* b2  = (const float*)d_in[6];
    const float* eps = (const float*)d_in[7];
    float* out = (float*)d_out;
    float* ws  = (float*)d_ws;
    ushort_t* Wb = (ushort_t*)((char*)d_ws + WB_OFF_BYTES);

    wb_kernel<<<(KTILES * NCT * 64 + 255) / 256, 256, 0, stream>>>(W0, W1, Wb, ws);

    void* args[] = { (void*)&x, (void*)&Wb, (void*)&b0, (void*)&b1,
                     (void*)&W2, (void*)&b2, (void*)&eps, (void*)&ws, (void*)&out };
    hipError_t e = hipLaunchCooperativeKernel((void*)fused_kernel,
                                              dim3(NBLK), dim3(1024),
                                              args, 0, stream);
    if (e != hipSuccess) {
        (void)hipGetLastError();           // clear, use proven R14 pipeline
        colmean_g<<<NROWS / 64, 1024, 0, stream>>>(x, Wb, b0, b1, ws);
        y2z_kernel<<<(NS * DIN * 64) / 256, 256, 0, stream>>>(W2, b2, eps, ws);
        pv_final_kernel<<<256, 256, 0, stream>>>(x, ws, eps, out, 256);
    }
}

// Round 16
// 50.747 us; speedup vs baseline: 2.1210x; 2.1210x over previous
//
#include <hip/hip_runtime.h>
#include <hip/hip_bf16.h>
#include <math.h>

#define NROWS 16384
#define DIN   784
#define DZ    100
#define NS    10
#define NCT   16           // 16 col-tiles x 16 = 256 cols (200 real + 56 zero pad)
#define KTILES 25          // 25 * 32 = 800 >= 784, tail frags zeroed
#define BND_THR 45.0f
#define KTPAD 520          // kt-stride in ushorts (1040B)

typedef unsigned short ushort_t;
typedef short bf16x8 __attribute__((ext_vector_type(8)));
typedef float f32x4  __attribute__((ext_vector_type(4)));

// ws: [0..199] colsums (atomic)  [200] pv sum  [203] done-counter
//     [208..8047] y2[s][i] = y*log2e
// byte 64KB..: Wb bf16 frag-swizzled W (400 KB)
#define WS_Y2 208
#define WB_OFF_BYTES (64u * 1024u)

__device__ __forceinline__ float softplus_fast(float v) {
    // ln(1+e^v) = (max(t,0) + log2(1+2^-|t|)) * ln2, t = v*log2e
    float t = v * 1.44269504088896f;
    return (fmaxf(t, 0.f)
            + __builtin_amdgcn_logf(1.f + __builtin_amdgcn_exp2f(-fabsf(t))))
           * 0.69314718055995f;
}
__device__ __forceinline__ unsigned pack2(float lo, float hi) {
    float2 f2; f2.x = lo; f2.y = hi;
    __hip_bfloat162 h2 = __float22bfloat162_rn(f2);
    return *reinterpret_cast<unsigned*>(&h2);
}

// ---- W -> bf16 B-frags + ws zero ----
// Wb[((kt*16 + ct)*64 + l)*8 + j] = W[ct*16 + (l&15)][kt*32 + (l>>4)*8 + j]
__global__ __launch_bounds__(256) void wb_kernel(
    const float* __restrict__ W0, const float* __restrict__ W1,
    ushort_t* __restrict__ Wb, float* __restrict__ ws)
{
    if (blockIdx.x == 0) ws[threadIdx.x] = 0.f;    // sums + counters
    int t = blockIdx.x * 256 + threadIdx.x;
    if (t >= KTILES * NCT * 64) return;
    int kt = t >> 10;
    int r  = t & 1023;
    int ct = r >> 6, l = r & 63;
    int col = ct * 16 + (l & 15);
    int k0  = kt * 32 + (l >> 4) * 8;
    uint4 o = make_uint4(0u, 0u, 0u, 0u);
    if (col < 200 && k0 < DIN) {
        const float* src = (col < 100 ? W0 + (size_t)col * DIN
                                      : W1 + (size_t)(col - 100) * DIN) + k0;
        float4 a = *(const float4*)src;
        float4 b = *(const float4*)(src + 4);
        o.x = pack2(a.x, a.y); o.y = pack2(a.z, a.w);
        o.z = pack2(b.x, b.y); o.w = pack2(b.z, b.w);
    }
    *(uint4*)(Wb + (size_t)t * 8) = o;
}

// ---- colmean h: B-STATIONARY waves. 256 blocks x 1024 thr (16 waves). ----
// Block = 64 rows; wave w owns col-tile w for ALL 4 rowtiles. Per kt:
// 1 B-load (global, dbuf) + 4 ds_read_b128 A-frags + 4 MFMA (4 indep chains).
// B traffic 4x lower than _g; epilogue needs no cross-wave reduce.
__global__ __launch_bounds__(1024) void colmean_h(
    const float* __restrict__ x, const ushort_t* __restrict__ Wb,
    const float* __restrict__ b0, const float* __restrict__ b1,
    float* __restrict__ ws)
{
    __shared__ ushort_t xls[4 * KTILES * KTPAD];   // 104 KB
    const int tid = threadIdx.x;
    const int lane = tid & 63, w = tid >> 6;
    const int row0 = blockIdx.x * 64;

    // ---- stage: coalesced x float4 reads -> bf16 A-frags in LDS, ONE barrier ----
    for (int slot = tid; slot < 6400; slot += 1024) {  // slot = r*100 + kt*4 + kc
        int r  = slot / 100;
        int sl = slot - r * 100;
        int kt = sl >> 2, kc = sl & 3;
        int k0 = kt * 32 + kc * 8;
        uint4 o = make_uint4(0u, 0u, 0u, 0u);
        if (k0 + 8 <= DIN) {
            const float* src = x + (size_t)(row0 + r) * DIN + k0;
            float4 a = *(const float4*)src, b = *(const float4*)(src + 4);
            o.x = pack2(a.x, a.y); o.y = pack2(a.z, a.w);
            o.z = pack2(b.x, b.y); o.w = pack2(b.z, b.w);
        }
        int l = (kc << 4) | (r & 15);
        *(uint4*)&xls[((size_t)(r >> 4) * KTILES + kt) * KTPAD + l * 8] = o;
    }
    __syncthreads();

    // ---- K-loop: zero barriers, named reg dbuf, B stationary per wave ----
    const ushort_t* ap  = xls + lane * 8;                  // + rt*KTILES*KTPAD + kt*KTPAD
    const ushort_t* wbp = Wb + (size_t)w * 512 + lane * 8; // + kt*8192

    f32x4 acc0 = (f32x4){0.f,0.f,0.f,0.f}, acc1 = acc0, acc2 = acc0, acc3 = acc0;

    bf16x8 Aa[4], Ab[4];
    uint4  Ba, Bb;

    auto ld = [&](int kt, bf16x8 (&A)[4], uint4& B) {
#pragma unroll
        for (int rt = 0; rt < 4; ++rt)
            A[rt] = *(const bf16x8*)(ap + (size_t)rt * KTILES * KTPAD + (size_t)kt * KTPAD);
        B = *(const uint4*)(wbp + (size_t)kt * 8192);
    };
    auto cp = [&](const bf16x8 (&A)[4], const uint4& B) {
        bf16x8 bf = *(const bf16x8*)&B;
        acc0 = __builtin_amdgcn_mfma_f32_16x16x32_bf16(A[0], bf, acc0, 0, 0, 0);
        acc1 = __builtin_amdgcn_mfma_f32_16x16x32_bf16(A[1], bf, acc1, 0, 0, 0);
        acc2 = __builtin_amdgcn_mfma_f32_16x16x32_bf16(A[2], bf, acc2, 0, 0, 0);
        acc3 = __builtin_amdgcn_mfma_f32_16x16x32_bf16(A[3], bf, acc3, 0, 0, 0);
    };

    ld(0, Aa, Ba);
    for (int i = 0; i < 12; ++i) {
        ld(2 * i + 1, Ab, Bb);
        cp(Aa, Ba);
        ld(2 * i + 2, Aa, Ba);
        cp(Ab, Bb);
    }
    cp(Aa, Ba);                            // kt = 24

    // ---- epilogue: wave owns complete 64-row sums for its 16 cols ----
    const int j = w * 16 + (lane & 15);
    const float bias = (j < 100) ? b0[j] : ((j < 200) ? b1[j - 100] : 0.f);
    float v = 0.f;
#pragma unroll
    for (int r = 0; r < 4; ++r)
        v += softplus_fast(acc0[r] + bias) + softplus_fast(acc1[r] + bias)
           + softplus_fast(acc2[r] + bias) + softplus_fast(acc3[r] + bias);
    v += __shfl_xor(v, 16);
    v += __shfl_xor(v, 32);
    if ((lane >> 4) == 0 && j < 200) atomicAdd(&ws[j], v);
}

// ---- y2 = (z @ W2.T + b2) * log2e with z computed inline from colsums ----
__global__ __launch_bounds__(256) void y2z_kernel(
    const float* __restrict__ W2, const float* __restrict__ b2,
    const float* __restrict__ eps, float* __restrict__ ws)
{
    int wid  = (int)((blockIdx.x * 256 + threadIdx.x) >> 6);
    int lane = threadIdx.x & 63;
    if (wid >= NS * DIN) return;
    int s = wid / DIN, i = wid % DIN;
    const float inv = 1.f / (float)NROWS;
    const float* wr = W2 + (size_t)i * DZ;
    const float* er = eps + (size_t)s * DZ;
    float p = 0.f;
    for (int d = lane; d < DZ; d += 64) {
        float zd = inv * (ws[d] + ws[100 + d] * er[d]);
        p += zd * wr[d];
    }
#pragma unroll
    for (int off = 32; off > 0; off >>= 1) p += __shfl_xor(p, off);
    if (lane == 0) ws[WS_Y2 + wid] = (p + b2[i]) * 1.4426950408889634f;
}

// ---- pv + fused finalization (last block computes Dkl + output) ----
// MFMA-certified bound: sum_i max(u,0) = 0.5*(n.y + |n|.|y|), u=(1-2x)*y2 (log2).
// bnd >= 45 => p < 2^-43 << ulp(0.001)/2 => term == ln(0.001) exactly.
__global__ __launch_bounds__(256, 4) void pv_final_kernel(
    const float* __restrict__ x, float* __restrict__ ws,
    const float* __restrict__ eps, float* __restrict__ out, int nblocks)
{
    __shared__ ushort_t yf[KTILES * 512];   // y2 B-frags (bf16)
    __shared__ ushort_t ya[KTILES * 512];   // |y2| B-frags
    __shared__ float bsum;
    __shared__ int lastflag;
    __shared__ float dred[256];
    const int tid = threadIdx.x;
    const int lane = tid & 63, w = tid >> 6;

    for (int idx = tid; idx < KTILES * 64; idx += 256) {
        int kt = idx >> 6, l = idx & 63;
        int ss = l & 15, k0 = kt * 32 + (l >> 4) * 8;
        uint4 o = make_uint4(0u, 0u, 0u, 0u), oa = o;
        if (ss < NS && k0 < DIN) {
            const float* src = ws + WS_Y2 + ss * DIN + k0;
            float4 a = *(const float4*)src, b = *(const float4*)(src + 4);
            o.x = pack2(a.x, a.y); o.y = pack2(a.z, a.w);
            o.z = pack2(b.x, b.y); o.w = pack2(b.z, b.w);
            oa.x = o.x & 0x7FFF7FFFu; oa.y = o.y & 0x7FFF7FFFu;
            oa.z = o.z & 0x7FFF7FFFu; oa.w = o.w & 0x7FFF7FFFu;
        }
        *(uint4*)(yf + (size_t)idx * 8) = o;
        *(uint4*)(ya + (size_t)idx * 8) = oa;
    }
    if (tid == 0) { bsum = 0.f; lastflag = 0; }
    __syncthreads();

    const int tile = blockIdx.x * 4 + w;       // 1024 tiles of 16 rows
    const int row  = tile * 16 + (lane & 15);
    const int kc   = lane >> 4;
    const int s    = lane & 15;
    const float* xp = x + (size_t)row * DIN;
    const float L001 = -6.90775527898f;        // ln(0.001f)

    f32x4 acc0 = (f32x4){0.f, 0.f, 0.f, 0.f};
    f32x4 acc1 = (f32x4){0.f, 0.f, 0.f, 0.f};
    float4 a0A, a1A, a0B, a1B;

    auto loadA = [&](int kt, float4& a0, float4& a1) {
        int k0 = kt * 32 + kc * 8;
        if (k0 + 8 > DIN) k0 = 768;            // junk ok: y frags zero there
        a0 = *(const float4*)(xp + k0);
        a1 = *(const float4*)(xp + k0 + 4);
    };
    auto comp = [&](int kt, const float4& a0, const float4& a1) {
        bf16x8 nf; unsigned* p = (unsigned*)&nf;
        p[0] = pack2(1.f - 2.f * a0.x, 1.f - 2.f * a0.y);
        p[1] = pack2(1.f - 2.f * a0.z, 1.f - 2.f * a0.w);
        p[2] = pack2(1.f - 2.f * a1.x, 1.f - 2.f * a1.y);
        p[3] = pack2(1.f - 2.f * a1.z, 1.f - 2.f * a1.w);
        bf16x8 na; unsigned* q = (unsigned*)&na;
        q[0] = p[0] & 0x7FFF7FFFu; q[1] = p[1] & 0x7FFF7FFFu;
        q[2] = p[2] & 0x7FFF7FFFu; q[3] = p[3] & 0x7FFF7FFFu;
        bf16x8 fy = *(const bf16x8*)(yf + (size_t)kt * 512 + lane * 8);
        bf16x8 fa = *(const bf16x8*)(ya + (size_t)kt * 512 + lane * 8);
        acc0 = __builtin_amdgcn_mfma_f32_16x16x32_bf16(nf, fy, acc0, 0, 0, 0);
        acc1 = __builtin_amdgcn_mfma_f32_16x16x32_bf16(na, fa, acc1, 0, 0, 0);
    };
    loadA(0, a0A, a1A);
    for (int i = 0; i < 12; ++i) {
        loadA(2 * i + 1, a0B, a1B);
        comp(2 * i, a0A, a1A);
        loadA(2 * i + 2, a0A, a1A);
        comp(2 * i + 1, a0B, a1B);
    }
    comp(24, a0A, a1A);

    float bnd[4];
#pragma unroll
    for (int r = 0; r < 4; ++r) bnd[r] = 0.5f * (acc0[r] + acc1[r]);
    float wsum;
    bool lslow = (s < NS) &&
        (fminf(fminf(bnd[0], bnd[1]), fminf(bnd[2], bnd[3])) < BND_THR);
    unsigned long long m = __ballot(lslow);
    if (m == 0ull) {
        wsum = 160.f * L001;                   // 16 rows x 10 samples, all certified
    } else {
        int nslow = 0;
        float slowsum = 0.f;
#pragma unroll
        for (int r = 0; r < 4; ++r) {
            unsigned long long mr = __ballot((s < NS) && (bnd[r] < BND_THR));
            nslow += (int)__popcll(mr);
            while (mr) {
                int src = (int)__ffsll(mr) - 1; mr &= (mr - 1);
                int ss = src & 15;
                int rrow = tile * 16 + (src >> 4) * 4 + r;
                const float* xq = x + (size_t)rrow * DIN;
                const float* yq = ws + WS_Y2 + ss * DIN;
                float a = 0.f;
                for (int i = lane; i < DIN; i += 64)
                    a -= __builtin_amdgcn_logf(
                        1.f + __builtin_amdgcn_exp2f((1.f - 2.f * xq[i]) * yq[i]));
#pragma unroll
                for (int off = 32; off > 0; off >>= 1) a += __shfl_xor(a, off);
                slowsum += __logf(__builtin_amdgcn_exp2f(a) + 0.001f);
            }
        }
        wsum = (float)(160 - nslow) * L001 + slowsum;
    }
    if (lane == 0) atomicAdd(&bsum, wsum);
    __syncthreads();

    if (tid == 0) {
        atomicAdd(&ws[200], bsum);
        __threadfence();
        unsigned old = atomicAdd((unsigned*)&ws[203], 1u);
        if (old == (unsigned)(nblocks - 1)) lastflag = 1;
    }
    __syncthreads();
    if (lastflag) {
        __threadfence();
        float contrib = 0.f;
        if (tid < DZ) {
            const float inv = 1.f / (float)NROWS;
            float mm = ws[tid] * inv;
            float cc = ws[100 + tid] * inv;
            contrib = 0.5f * __logf(cc);
#pragma unroll
            for (int ss2 = 0; ss2 < NS; ++ss2) {
                float e = eps[ss2 * DZ + tid];
                float zz = mm + cc * e;
                contrib += (0.5f * cc * e * e - 0.5f * zz * zz) * (1.f / NS);
            }
        }
        dred[tid] = contrib;
        __syncthreads();
        for (int off = 128; off > 0; off >>= 1) {
            if (tid < off) dred[tid] += dred[tid + off];
            __syncthreads();
        }
        if (tid == 0) {
            float S = atomicAdd(&ws[200], 0.f);
            float E = S * (1.f / ((float)NROWS * (float)NS));
            out[0] = -(E + dred[0]);
        }
    }
}

extern "C" void kernel_launch(void* const* d_in, const int* in_sizes, int n_in,
                              void* d_out, int out_size, void* d_ws, size_t ws_size,
                              hipStream_t stream)
{
    const float* x   = (const float*)d_in[0];
    const float* W0  = (const float*)d_in[1];
    const float* b0  = (const float*)d_in[2];
    const float* W1  = (const float*)d_in[3];
    const float* b1  = (const float*)d_in[4];
    const float* W2  = (const float*)d_in[5];
    const float* b2  = (const float*)d_in[6];
    const float* eps = (const float*)d_in[7];
    float* out = (float*)d_out;
    float* ws  = (float*)d_ws;
    ushort_t* Wb = (ushort_t*)((char*)d_ws + WB_OFF_BYTES);

    wb_kernel<<<(KTILES * NCT * 64 + 255) / 256, 256, 0, stream>>>(W0, W1, Wb, ws);
    colmean_h<<<NROWS / 64, 1024, 0, stream>>>(x, Wb, b0, b1, ws);
    y2z_kernel<<<(NS * DIN * 64) / 256, 256, 0, stream>>>(W2, b2, eps, ws);
    pv_final_kernel<<<256, 256, 0, stream>>>(x, ws, eps, out, 256);
}